// Round 12
// baseline (203.570 us; speedup 1.0000x reference)
//
#include <hip/hip_runtime.h>

// out[b,d,t] = sum_c x[b,c,t] * weights[subjects[b],c,d]
// B=256, C=270, T=1024, NSUB=200. fp32 in/out, bf16 MFMA internally.
//
// DMA staging (global_load_lds) of fp32 tiles into padded LDS (R11 layout,
// 2-way bank-free). R12 change: fragment build uses ds_read2_b32 (dual
// 8-bit dword offsets) -> ONE LDS instruction per packed u32 instead of
// two scalar ds_read_b32. R10/R11 showed the wall is LDS ISSUE COUNT
// (48 reads/wave-step ~= the whole 232us wall; padding changed data
// cycles, not time). 24 ops/wave-step now.
//   A pair (c,c+1):  offset0 = m*16, offset1 = m*16+72   (RA=72)
//   B pair (c,c+1):  offset0 = n*16, offset1 = n*16+128  (pair stride 264)
//   j-dimension: 4 precomputed LDS byte addresses (strides 2304B / 4224B).
// Inline-asm reads + s_waitcnt lgkmcnt(0) + sched_barrier(0) before use
// (rule #18). k-order freedom: A and B both use c = 8j + 2lg + {0,1}.
// Tail tile clamps global addresses and zero-masks invalid B k-slots.

#define C_    270
#define T_    1024
#define B_    256
#define NSUB_ 200

#define BM 64        // d-tile
#define BN 128       // t-tile
#define BK 32        // c-step
#define RPB 264      // u32 stride of one c-row-PAIR of B (256 data + 8 pad)
#define RA  72       // u32 stride of one c-row of A (64 data + 8 pad)
#define LB_U32 (16 * RPB)           // 4224 u32  [c/2][2][128+pad] fp32
#define LA_U32 (32 * RA)            // 2304 u32  [c][64+pad] fp32
#define BUF_U32 (LB_U32 + LA_U32)   // 6528 u32 = 26112 B per buffer

typedef __attribute__((ext_vector_type(8))) short bf16x8;
typedef __attribute__((ext_vector_type(4))) float f32x4;
typedef __attribute__((ext_vector_type(2))) float f32x2;
typedef __attribute__((ext_vector_type(4))) int i32x4;

__device__ __forceinline__ unsigned pk(float lo, float hi) {
    // v_cvt_pk_bf16_f32: RNE, lo -> low 16 bits. No builtin on gfx950.
    unsigned r;
    asm("v_cvt_pk_bf16_f32 %0, %1, %2" : "=v"(r) : "v"(lo), "v"(hi));
    return r;
}

// Dual-offset LDS read: d.x = LDS[a + O0*4], d.y = LDS[a + O1*4].
#define DS2(d, a, O0, O1)                                             \
    asm volatile("ds_read2_b32 %0, %1 offset0:" O0 " offset1:" O1     \
                 : "=v"(d) : "v"(a) : "memory")

// Async global->LDS. Dest = wave-uniform base + lane*width.
__device__ __forceinline__ void gl2lds16(const float* g, const unsigned* l) {
    __builtin_amdgcn_global_load_lds(
        (__attribute__((address_space(1))) void*)g,
        (__attribute__((address_space(3))) void*)l, 16, 0, 0);
}
__device__ __forceinline__ void gl2lds4(const float* g, const unsigned* l) {
    __builtin_amdgcn_global_load_lds(
        (__attribute__((address_space(1))) void*)g,
        (__attribute__((address_space(3))) void*)l, 4, 0, 0);
}

__global__ __launch_bounds__(256, 3)
void subj_layers_kernel(const float* __restrict__ x,
                        const int* __restrict__ subjects,
                        const float* __restrict__ w,
                        float* __restrict__ out)
{
    __shared__ unsigned lds[2][BUF_U32];

    const int tid  = threadIdx.x;
    const int lane = tid & 63;
    const int wid  = tid >> 6;
    const int wr   = wid >> 1;   // wave d-row 0..1 (32 d each)
    const int wc   = wid & 1;    // wave t-col 0..1 (64 t each)
    const int lg   = lane >> 4;
    const int lr   = lane & 15;
    const int l5   = lane >> 5, l31 = lane & 31;  // B staging split

    // Bijective XCD-chunk swizzle (10240 = 8 x 1280), d-tile fastest.
    const int bid  = (blockIdx.x & 7) * 1280 + (blockIdx.x >> 3);
    const int b    = bid / 40;
    const int rem  = bid % 40;
    const int d0   = (rem % 5) * BM;   // 0,64,128,192,256
    const int t0   = (rem / 5) * BN;   // 0..896

    int sub = subjects[b];
    sub = sub < 0 ? 0 : (sub >= NSUB_ ? NSUB_ - 1 : sub);
    const float* __restrict__ wsub = w + (size_t)sub * (C_ * C_);
    const float* __restrict__ xb   = x + (size_t)b * (C_ * T_);
    const float* wLast = w + (size_t)NSUB_ * C_ * C_ - 1;  // last valid elem

    // ---- per-lane staging base pointers ----
    const float* xg = xb + (size_t)l5 * T_ + t0 + 4 * l31;
    const float* ag = wsub + d0 + lane;

    auto stage_full = [&](unsigned* L, int c0) {
        #pragma unroll
        for (int ii = 0; ii < 4; ++ii) {
            const int i = wid + 4 * ii;
            gl2lds16(xg + (size_t)(c0 + 2 * i) * T_, L + i * RPB);
        }
        #pragma unroll
        for (int ii = 0; ii < 8; ++ii) {
            const int i = wid + 4 * ii;
            gl2lds4(ag + (size_t)(c0 + i) * C_, L + LB_U32 + i * RA);
        }
    };

    auto stage_tail = [&](unsigned* L) {
        #pragma unroll
        for (int ii = 0; ii < 4; ++ii) {
            const int i = wid + 4 * ii;
            int c = 256 + 2 * i + l5; c = c < C_ ? c : C_ - 1;
            gl2lds16(xb + (size_t)c * T_ + t0 + 4 * l31, L + i * RPB);
        }
        #pragma unroll
        for (int ii = 0; ii < 8; ++ii) {
            const int i = wid + 4 * ii;
            int c = 256 + i; c = c < C_ ? c : C_ - 1;
            const float* ga = ag + (size_t)c * C_;
            if (ga > wLast) ga = wLast;
            gl2lds4(ga, L + LB_U32 + i * RA);
        }
    };

    f32x4 acc[2][4];
    #pragma unroll
    for (int m = 0; m < 2; ++m)
        #pragma unroll
        for (int n = 0; n < 4; ++n)
            acc[m][n] = (f32x4){0.f, 0.f, 0.f, 0.f};

    // Fragment build: slot j = pk(c=8j+2lg, c=8j+2lg+1). Same k-mapping on
    // A and B -> exact dot product.
    //   A elem (c,d): u32 c*RA + d.          B elem (c,t): (c>>1)*RPB + (c&1)*128 + t.
    auto compute = [&](const unsigned* L, bool tail) {
        const unsigned Ab = (unsigned)(size_t)(L + LB_U32)
                          + (unsigned)((2 * lg * RA + wr * 32 + lr) * 4);
        const unsigned Bb = (unsigned)(size_t)L
                          + (unsigned)((lg * RPB + wc * 64 + lr) * 4);
        const unsigned a0 = Ab, a1 = Ab + 8 * RA * 4, a2 = Ab + 16 * RA * 4, a3 = Ab + 24 * RA * 4;
        const unsigned b0 = Bb, b1 = Bb + 4 * RPB * 4, b2 = Bb + 8 * RPB * 4, b3 = Bb + 12 * RPB * 4;

        f32x2 A0[4], A1[4], Bp[4][4];
        DS2(A0[0], a0, "0", "72");   DS2(A0[1], a1, "0", "72");
        DS2(A0[2], a2, "0", "72");   DS2(A0[3], a3, "0", "72");
        DS2(A1[0], a0, "16", "88");  DS2(A1[1], a1, "16", "88");
        DS2(A1[2], a2, "16", "88");  DS2(A1[3], a3, "16", "88");
        DS2(Bp[0][0], b0, "0", "128");  DS2(Bp[0][1], b1, "0", "128");
        DS2(Bp[0][2], b2, "0", "128");  DS2(Bp[0][3], b3, "0", "128");
        DS2(Bp[1][0], b0, "16", "144"); DS2(Bp[1][1], b1, "16", "144");
        DS2(Bp[1][2], b2, "16", "144"); DS2(Bp[1][3], b3, "16", "144");
        DS2(Bp[2][0], b0, "32", "160"); DS2(Bp[2][1], b1, "32", "160");
        DS2(Bp[2][2], b2, "32", "160"); DS2(Bp[2][3], b3, "32", "160");
        DS2(Bp[3][0], b0, "48", "176"); DS2(Bp[3][1], b1, "48", "176");
        DS2(Bp[3][2], b2, "48", "176"); DS2(Bp[3][3], b3, "48", "176");

        asm volatile("s_waitcnt lgkmcnt(0)" ::: "memory");
        __builtin_amdgcn_sched_barrier(0);

        bf16x8 af[2], bfr[4];
        {
            i32x4 u;
            #pragma unroll
            for (int j = 0; j < 4; ++j) u[j] = (int)pk(A0[j].x, A0[j].y);
            af[0] = __builtin_bit_cast(bf16x8, u);
            #pragma unroll
            for (int j = 0; j < 4; ++j) u[j] = (int)pk(A1[j].x, A1[j].y);
            af[1] = __builtin_bit_cast(bf16x8, u);
        }
        #pragma unroll
        for (int n = 0; n < 4; ++n) {
            i32x4 u;
            #pragma unroll
            for (int j = 0; j < 4; ++j) u[j] = (int)pk(Bp[n][j].x, Bp[n][j].y);
            if (tail) {                 // c = 256 + 8j + 2lg + {0,1}
                u[2] = 0; u[3] = 0;     // c >= 272: invalid
                if (lg == 3) u[1] = 0;  // c = 270,271: invalid
            }
            bfr[n] = __builtin_bit_cast(bf16x8, u);
        }
        #pragma unroll
        for (int m = 0; m < 2; ++m)
            #pragma unroll
            for (int n = 0; n < 4; ++n)
                acc[m][n] = __builtin_amdgcn_mfma_f32_16x16x32_bf16(af[m], bfr[n], acc[m][n], 0, 0, 0);
    };

    // ---- pipeline: issue tile k+1 DMA, compute tile k; __syncthreads
    // drains vmcnt (tile k+1 resident) and protects buffers. ----
    stage_full(&lds[0][0], 0);
    __syncthreads();

    #pragma unroll 1
    for (int k = 0; k < 7; ++k) {
        stage_full(&lds[(k + 1) & 1][0], (k + 1) * BK);  // tiles 1..7
        compute(&lds[k & 1][0], false);                  // tiles 0..6
        __syncthreads();
    }
    stage_tail(&lds[0][0]);                 // tile 8 -> buf0
    compute(&lds[1][0], false);             // tile 7
    __syncthreads();
    compute(&lds[0][0], true);              // tile 8 (masked)

    // ---- epilogue: C/D layout col=lane&15, row=(lane>>4)*4+reg ----
    float* outb = out + (size_t)b * (C_ * T_);
    #pragma unroll
    for (int m = 0; m < 2; ++m) {
        const int dbase = d0 + wr * 32 + m * 16 + 4 * lg;
        #pragma unroll
        for (int n = 0; n < 4; ++n) {
            const int t = t0 + wc * 64 + n * 16 + lr;
            #pragma unroll
            for (int rr = 0; rr < 4; ++rr) {
                const int d = dbase + rr;
                if (d < C_)
                    outb[(size_t)d * T_ + t] = acc[m][n][rr];
            }
        }
    }
}

extern "C" void kernel_launch(void* const* d_in, const int* in_sizes, int n_in,
                              void* d_out, int out_size, void* d_ws, size_t ws_size,
                              hipStream_t stream)
{
    const float* x        = (const float*)d_in[0];
    const int*   subjects = (const int*)d_in[1];
    const float* w        = (const float*)d_in[2];
    float* out            = (float*)d_out;

    dim3 grid(B_ * 40);  // 256 batches * (5 d-tiles * 8 t-tiles) = 10240
    dim3 block(256);
    hipLaunchKernelGGL(subj_layers_kernel, grid, block, 0, stream,
                       x, subjects, w, out);
}